// Round 5
// baseline (284.058 us; speedup 1.0000x reference)
//
#include <hip/hip_runtime.h>
#include <cstdint>
#include <cstddef>

#define Bn 64
#define Tn 2048
#define Un 512
#define QSn 512
#define MSn 512

using f32x16 = __attribute__((ext_vector_type(16))) float;
using bf16x8 = __attribute__((ext_vector_type(8))) short;

__device__ __forceinline__ unsigned short f2bf(float x) {
    unsigned int u = __float_as_uint(x);
    u += 0x7FFFu + ((u >> 16) & 1u);
    return (unsigned short)(u >> 16);
}

__device__ __forceinline__ float tanh_fast(float x) {
    // tanh(x) = 1 - 2/(e^{2x}+1). exp->inf gives 1, exp->0 gives -1; no clamp.
    float e = exp2f(x * 2.885390043258667f);   // e^{2x}
    return 1.f - 2.f * __builtin_amdgcn_rcpf(e + 1.f);
}

// ---------------- Wm f32 -> bf16 pre-convert ----------------
__global__ __launch_bounds__(256) void cvt_kernel(const float* __restrict__ src,
                                                  unsigned short* __restrict__ dst) {
    int i = blockIdx.x * 256 + threadIdx.x;  // one float4 per thread
    float4 v = *(const float4*)(src + (size_t)i * 4);
    ushort4 h = { f2bf(v.x), f2bf(v.y), f2bf(v.z), f2bf(v.w) };
    *(ushort4*)&dst[(size_t)i * 4] = h;
}

// ---------------- pq = query @ Wq^T : [B,U] ----------------
__global__ __launch_bounds__(128) void pq_kernel(const float* __restrict__ query,
                                                 const float* __restrict__ Wq,
                                                 float* __restrict__ pq) {
    __shared__ float ql[QSn];
    const int b = blockIdx.x;
    const int quad = blockIdx.y;
    const int tid = threadIdx.x;
    for (int i = tid; i < QSn; i += 128) ql[i] = query[(size_t)b * QSn + i];
    __syncthreads();
    const int u = quad * 128 + tid;
    const float* w = Wq + (size_t)u * QSn;
    float a0 = 0.f, a1 = 0.f;
    #pragma unroll 4
    for (int k = 0; k < QSn; k += 8) {
        float4 w0 = *(const float4*)(w + k);
        float4 w1 = *(const float4*)(w + k + 4);
        float4 q0 = *(const float4*)(ql + k);
        float4 q1 = *(const float4*)(ql + k + 4);
        a0 += w0.x * q0.x + w0.y * q0.y + w0.z * q0.z + w0.w * q0.w;
        a1 += w1.x * q1.x + w1.y * q1.y + w1.z * q1.z + w1.w * q1.w;
    }
    pq[(size_t)b * Un + u] = a0 + a1;
}

// ---------------- fused score GEMM (v5: depth-2 A prefetch, 3 LDS bufs) ----------------
// 256 threads = 4 waves. Block tile 64t x 256u (uh split over 2 blocks, merged in
// softmax). Wave tile 64x64 = 2x2 mfma_32x32x16.
// Per iter kt (issue order pinned, vmcnt FIFO-counted):
//   1. B(kt+1) -> breg[(kt+1)&1]          (L2, 8x16B)
//   2. A(kt+2) -> sA slot (kt&1)          (HBM, 4x float4)   [depth 2!]
//   3. MFMA: Alds[kt%3] x breg[kt&1]      (B wait = vmcnt(16), counted)
//   4. cvt+ds_write A(kt+1) -> Alds[(kt+1)%3]  (A wait = vmcnt(12), ~1.4 iters slack)
//   5. lgkmcnt(0); raw s_barrier          (no vmcnt drain -> loads fly across)
#define TM 64
#define BKt 64

__global__ __launch_bounds__(256, 3) void score_kernel(const float* __restrict__ keys,
                                                       const unsigned short* __restrict__ WmB,
                                                       const float* __restrict__ pq,
                                                       const float* __restrict__ Wa,
                                                       float* __restrict__ spart) {
    __shared__ __align__(16) unsigned short Alds[3][TM * BKt];  // 24 KB
    __shared__ float sc_lds[4][TM];

    const int tid = threadIdx.x;
    const int lane = tid & 63;
    const int w = tid >> 6;
    const int lc = lane & 31;
    const int l5 = lane >> 5;
    const int b = blockIdx.y;
    const int tt = blockIdx.x >> 1;
    const int uh = blockIdx.x & 1;
    const int t0 = tt * TM;
    const int u0 = uh * 256 + w * 64;

    // A staging: thread owns row srow, two 8-elem granules scg, scg+1
    const int srow = tid >> 2;
    const int scg  = (tid & 3) * 2;
    const float* gA = keys + ((size_t)(b * Tn + t0 + srow)) * MSn + scg * 8;
    const int woff0 = srow * BKt + ((scg ^ (srow & 7)) * 8);
    const int woff1 = srow * BKt + (((scg + 1) ^ (srow & 7)) * 8);

    const unsigned short* gB0 = WmB + ((size_t)(u0 + lc)) * MSn + l5 * 8;
    const unsigned short* gB1 = gB0 + (size_t)32 * MSn;

    f32x16 acc[2][2];
    #pragma unroll
    for (int mf = 0; mf < 2; ++mf)
        #pragma unroll
        for (int nf = 0; nf < 2; ++nf)
            #pragma unroll
            for (int r = 0; r < 16; ++r) acc[mf][nf][r] = 0.f;

    bf16x8 breg[2][4][2];
    float4 sA[2][4];   // two in-flight A tiles (indices always compile-time via unroll)

    // ---- prologue: B(0); A(0)->sA[0]; A(1)->sA[1]; write A(0)->buf0; barrier
    {
        #pragma unroll
        for (int ks = 0; ks < 4; ++ks) {
            breg[0][ks][0] = *(const bf16x8*)(gB0 + ks * 16);
            breg[0][ks][1] = *(const bf16x8*)(gB1 + ks * 16);
        }
        __builtin_amdgcn_sched_barrier(0);
        sA[0][0] = *(const float4*)(gA);
        sA[0][1] = *(const float4*)(gA + 4);
        sA[0][2] = *(const float4*)(gA + 8);
        sA[0][3] = *(const float4*)(gA + 12);
        __builtin_amdgcn_sched_barrier(0);
        const float* g1 = gA + BKt;
        sA[1][0] = *(const float4*)(g1);
        sA[1][1] = *(const float4*)(g1 + 4);
        sA[1][2] = *(const float4*)(g1 + 8);
        sA[1][3] = *(const float4*)(g1 + 12);
        __builtin_amdgcn_sched_barrier(0);
        ushort4 h0 = { f2bf(sA[0][0].x), f2bf(sA[0][0].y), f2bf(sA[0][0].z), f2bf(sA[0][0].w) };
        ushort4 h1 = { f2bf(sA[0][1].x), f2bf(sA[0][1].y), f2bf(sA[0][1].z), f2bf(sA[0][1].w) };
        ushort4 h2 = { f2bf(sA[0][2].x), f2bf(sA[0][2].y), f2bf(sA[0][2].z), f2bf(sA[0][2].w) };
        ushort4 h3 = { f2bf(sA[0][3].x), f2bf(sA[0][3].y), f2bf(sA[0][3].z), f2bf(sA[0][3].w) };
        *(ushort4*)&Alds[0][woff0]     = h0;
        *(ushort4*)&Alds[0][woff0 + 4] = h1;
        *(ushort4*)&Alds[0][woff1]     = h2;
        *(ushort4*)&Alds[0][woff1 + 4] = h3;
    }
    asm volatile("s_waitcnt lgkmcnt(0)" ::: "memory");
    __builtin_amdgcn_s_barrier();

    #pragma unroll
    for (int kt = 0; kt < 8; ++kt) {
        // 1) B loads for kt+1 (consumed next iter; counted-vmcnt hidden)
        if (kt < 7) {
            #pragma unroll
            for (int ks = 0; ks < 4; ++ks) {
                breg[(kt + 1) & 1][ks][0] = *(const bf16x8*)(gB0 + (kt + 1) * BKt + ks * 16);
                breg[(kt + 1) & 1][ks][1] = *(const bf16x8*)(gB1 + (kt + 1) * BKt + ks * 16);
            }
            __builtin_amdgcn_sched_barrier(0);
        }
        // 2) A loads for kt+2 into slot (kt&1)  [A(kt+1) lives in slot ((kt+1)&1)]
        if (kt < 6) {
            const float* g = gA + (kt + 2) * BKt;
            sA[kt & 1][0] = *(const float4*)(g);
            sA[kt & 1][1] = *(const float4*)(g + 4);
            sA[kt & 1][2] = *(const float4*)(g + 8);
            sA[kt & 1][3] = *(const float4*)(g + 12);
            __builtin_amdgcn_sched_barrier(0);
        }

        // 3) MFMA: A[kt] from Alds[kt%3], B[kt] from regs issued last iter
        {
            const unsigned short* lA = &Alds[kt % 3][0];
            #pragma unroll
            for (int ks = 0; ks < 4; ++ks) {
                bf16x8 af[2];
                #pragma unroll
                for (int mf = 0; mf < 2; ++mf) {
                    int r = mf * 32 + lc;
                    int g = ks * 2 + l5;
                    af[mf] = *(const bf16x8*)&lA[r * BKt + ((g ^ (r & 7)) * 8)];
                }
                #pragma unroll
                for (int mf = 0; mf < 2; ++mf)
                    #pragma unroll
                    for (int nf = 0; nf < 2; ++nf)
                        acc[mf][nf] = __builtin_amdgcn_mfma_f32_32x32x16_bf16(
                            af[mf], breg[kt & 1][ks][nf], acc[mf][nf], 0, 0, 0);
            }
        }
        __builtin_amdgcn_sched_barrier(0);

        // 4) cvt + ds_write A(kt+1) (loads issued at iter kt-1 -> ~1.4 iters slack)
        if (kt < 7) {
            const float4* s = sA[(kt + 1) & 1];
            ushort4 h0 = { f2bf(s[0].x), f2bf(s[0].y), f2bf(s[0].z), f2bf(s[0].w) };
            ushort4 h1 = { f2bf(s[1].x), f2bf(s[1].y), f2bf(s[1].z), f2bf(s[1].w) };
            ushort4 h2 = { f2bf(s[2].x), f2bf(s[2].y), f2bf(s[2].z), f2bf(s[2].w) };
            ushort4 h3 = { f2bf(s[3].x), f2bf(s[3].y), f2bf(s[3].z), f2bf(s[3].w) };
            unsigned short* d = &Alds[(kt + 1) % 3][0];
            *(ushort4*)&d[woff0]     = h0;
            *(ushort4*)&d[woff0 + 4] = h1;
            *(ushort4*)&d[woff1]     = h2;
            *(ushort4*)&d[woff1 + 4] = h3;
        }
        // 5) drain LDS only; global loads stay in flight across the barrier
        asm volatile("s_waitcnt lgkmcnt(0)" ::: "memory");
        __builtin_amdgcn_s_barrier();
    }

    // ---- epilogue: partial score = sum_u tanh(vals + pq[u]) * Wa[u]
    // C layout: col(u) = lc, row(t) = mf*32 + (r&3) + 8*(r>>2) + 4*l5
    float pqv[2], wav[2];
    #pragma unroll
    for (int nf = 0; nf < 2; ++nf) {
        int u = u0 + nf * 32 + lc;
        pqv[nf] = pq[(size_t)b * Un + u];
        wav[nf] = Wa[u];
    }
    #pragma unroll
    for (int mf = 0; mf < 2; ++mf) {
        #pragma unroll
        for (int r = 0; r < 16; ++r) {
            float s = tanh_fast(acc[mf][0][r] + pqv[0]) * wav[0]
                    + tanh_fast(acc[mf][1][r] + pqv[1]) * wav[1];
            s += __shfl_xor(s, 16);
            s += __shfl_xor(s, 8);
            s += __shfl_xor(s, 4);
            s += __shfl_xor(s, 2);
            s += __shfl_xor(s, 1);
            if (lc == 0)
                sc_lds[w][mf * 32 + (r & 3) + 8 * (r >> 2) + 4 * l5] = s;
        }
    }
    __syncthreads();
    if (tid < TM) {
        float s = sc_lds[0][tid] + sc_lds[1][tid] + sc_lds[2][tid] + sc_lds[3][tid];
        spart[((size_t)(uh * Bn + b)) * Tn + t0 + tid] = s;
    }
}

// ---------------- merge partials + softmax ----------------
__global__ __launch_bounds__(256) void softmax_kernel(const float* __restrict__ spart,
                                                      float* __restrict__ score_out,
                                                      float* __restrict__ weight) {
    const int b = blockIdx.x, tid = threadIdx.x;
    const int lane = tid & 63, wid = tid >> 6;
    __shared__ float red[4];
    const float* s0 = spart + (size_t)b * Tn;
    const float* s1 = spart + ((size_t)(Bn + b)) * Tn;
    float v[8];
    float mx = -1e30f;
    #pragma unroll
    for (int i = 0; i < 8; ++i) {
        int t = tid + i * 256;
        v[i] = s0[t] + s1[t];
        score_out[(size_t)b * Tn + t] = v[i];
        mx = fmaxf(mx, v[i]);
    }
    #pragma unroll
    for (int off = 32; off; off >>= 1) mx = fmaxf(mx, __shfl_xor(mx, off));
    if (lane == 0) red[wid] = mx;
    __syncthreads();
    mx = fmaxf(fmaxf(red[0], red[1]), fmaxf(red[2], red[3]));
    float sum = 0.f;
    #pragma unroll
    for (int i = 0; i < 8; ++i) { v[i] = expf(v[i] - mx); sum += v[i]; }
    #pragma unroll
    for (int off = 32; off; off >>= 1) sum += __shfl_xor(sum, off);
    __syncthreads();
    if (lane == 0) red[wid] = sum;
    __syncthreads();
    sum = red[0] + red[1] + red[2] + red[3];
    float inv = 1.f / sum;
    #pragma unroll
    for (int i = 0; i < 8; ++i) weight[(size_t)b * Tn + tid + i * 256] = v[i] * inv;
}

// ---------------- context partials: 32 t-chunks per batch, float4/lane ----------------
#define NCH 32
__global__ __launch_bounds__(128) void ctx_partial_kernel(const float* __restrict__ keys,
                                                          const float* __restrict__ weight,
                                                          float* __restrict__ partial) {
    __shared__ float wl[64];
    const int b = blockIdx.x, chunk = blockIdx.y, tid = threadIdx.x;
    const int t0 = chunk * 64;
    if (tid < 64) wl[tid] = weight[(size_t)b * Tn + t0 + tid];
    __syncthreads();
    float4 acc = { 0.f, 0.f, 0.f, 0.f };
    const float4* kp = (const float4*)(keys + ((size_t)b * Tn + t0) * MSn) + tid;
    #pragma unroll 4
    for (int t = 0; t < 64; ++t) {
        float4 kv = kp[(size_t)t * (MSn / 4)];
        float w = wl[t];
        acc.x += w * kv.x;
        acc.y += w * kv.y;
        acc.z += w * kv.z;
        acc.w += w * kv.w;
    }
    *(float4*)&partial[((size_t)b * NCH + chunk) * MSn + tid * 4] = acc;
}

// ---------------- reduce partials -> total_context ----------------
__global__ __launch_bounds__(512) void ctx_reduce_kernel(const float* __restrict__ partial,
                                                         float* __restrict__ ctx) {
    const int b = blockIdx.x, m = threadIdx.x;
    float s = 0.f;
    #pragma unroll
    for (int c = 0; c < NCH; ++c) s += partial[((size_t)b * NCH + c) * MSn + m];
    ctx[(size_t)b * MSn + m] = s;
}

extern "C" void kernel_launch(void* const* d_in, const int* in_sizes, int n_in,
                              void* d_out, int out_size, void* d_ws, size_t ws_size,
                              hipStream_t stream) {
    const float* query = (const float*)d_in[0];
    const float* keys  = (const float*)d_in[1];
    const float* Wq    = (const float*)d_in[2];
    const float* Wm    = (const float*)d_in[3];
    const float* Wa    = (const float*)d_in[4];

    float* ctx_out   = (float*)d_out;                    // [64][512]
    float* score_out = (float*)d_out + (size_t)Bn * MSn; // [64][2048]

    char* ws = (char*)d_ws;
    float* ws_pq      = (float*)(ws);                    // 128 KB
    float* ws_weight  = (float*)(ws + 131072);           // 512 KB
    float* ws_spart   = (float*)(ws + 655360);           // 1 MB  [2][64][2048]
    float* ws_partial = (float*)(ws + 1703936);          // 4 MB  [64][32][512]
    unsigned short* ws_wmbf = (unsigned short*)(ws + 5898240);  // 512 KB

    cvt_kernel<<<(Un * MSn / 4) / 256, 256, 0, stream>>>(Wm, ws_wmbf);
    pq_kernel<<<dim3(Bn, 4), 128, 0, stream>>>(query, Wq, ws_pq);
    score_kernel<<<dim3((Tn / TM) * 2, Bn), 256, 0, stream>>>(keys, ws_wmbf, ws_pq, Wa, ws_spart);
    softmax_kernel<<<Bn, 256, 0, stream>>>(ws_spart, score_out, ws_weight);
    ctx_partial_kernel<<<dim3(Bn, NCH), 128, 0, stream>>>(keys, ws_weight, ws_partial);
    ctx_reduce_kernel<<<Bn, 512, 0, stream>>>(ws_partial, ctx_out);
}

// Round 6
// 281.210 us; speedup vs baseline: 1.0101x; 1.0101x over previous
//
#include <hip/hip_runtime.h>
#include <cstdint>
#include <cstddef>

#define Bn 64
#define Tn 2048
#define Un 512
#define QSn 512
#define MSn 512

using f32x16 = __attribute__((ext_vector_type(16))) float;
using bf16x8 = __attribute__((ext_vector_type(8))) short;

__device__ __forceinline__ unsigned short f2bf(float x) {
    unsigned int u = __float_as_uint(x);
    u += 0x7FFFu + ((u >> 16) & 1u);
    return (unsigned short)(u >> 16);
}

__device__ __forceinline__ unsigned int pk2bf(float lo, float hi) {
    unsigned int r;
    asm("v_cvt_pk_bf16_f32 %0, %1, %2" : "=v"(r) : "v"(lo), "v"(hi));
    return r;
}

__device__ __forceinline__ bf16x8 cvt8(float4 a, float4 b) {
    union { unsigned int u[4]; bf16x8 v; } r;
    r.u[0] = pk2bf(a.x, a.y);
    r.u[1] = pk2bf(a.z, a.w);
    r.u[2] = pk2bf(b.x, b.y);
    r.u[3] = pk2bf(b.z, b.w);
    return r.v;
}

__device__ __forceinline__ float tanh_fast(float x) {
    float e = exp2f(x * 2.885390043258667f);   // e^{2x}
    return 1.f - 2.f * __builtin_amdgcn_rcpf(e + 1.f);
}

// async global->LDS, 16B per lane; LDS base must be wave-uniform
#define GLOAD(G, L) __builtin_amdgcn_global_load_lds( \
    (const __attribute__((address_space(1))) void*)(G), \
    (__attribute__((address_space(3))) void*)(L), 16, 0, 0)

// counted-vmcnt barrier: drain nothing newer than N, raw barrier, sched fence
#define PIPE_BAR(N) do { \
    asm volatile("s_waitcnt vmcnt(" #N ")" ::: "memory"); \
    __builtin_amdgcn_s_barrier(); \
    __builtin_amdgcn_sched_barrier(0); } while (0)

// ---------------- Wm f32 -> bf16 pre-convert ----------------
__global__ __launch_bounds__(256) void cvt_kernel(const float* __restrict__ src,
                                                  unsigned short* __restrict__ dst) {
    int i = blockIdx.x * 256 + threadIdx.x;  // one float4 per thread
    float4 v = *(const float4*)(src + (size_t)i * 4);
    ushort4 h = { f2bf(v.x), f2bf(v.y), f2bf(v.z), f2bf(v.w) };
    *(ushort4*)&dst[(size_t)i * 4] = h;
}

// ---------------- pq = query @ Wq^T : [B,U] ----------------
__global__ __launch_bounds__(128) void pq_kernel(const float* __restrict__ query,
                                                 const float* __restrict__ Wq,
                                                 float* __restrict__ pq) {
    __shared__ float ql[QSn];
    const int b = blockIdx.x;
    const int quad = blockIdx.y;
    const int tid = threadIdx.x;
    for (int i = tid; i < QSn; i += 128) ql[i] = query[(size_t)b * QSn + i];
    __syncthreads();
    const int u = quad * 128 + tid;
    const float* w = Wq + (size_t)u * QSn;
    float a0 = 0.f, a1 = 0.f;
    #pragma unroll 4
    for (int k = 0; k < QSn; k += 8) {
        float4 w0 = *(const float4*)(w + k);
        float4 w1 = *(const float4*)(w + k + 4);
        float4 q0 = *(const float4*)(ql + k);
        float4 q1 = *(const float4*)(ql + k + 4);
        a0 += w0.x * q0.x + w0.y * q0.y + w0.z * q0.z + w0.w * q0.w;
        a1 += w1.x * q1.x + w1.y * q1.y + w1.z * q1.z + w1.w * q1.w;
    }
    pq[(size_t)b * Un + u] = a0 + a1;
}

// ---------------- fused score GEMM (v6: DMA-A f32, depth-2, counted vmcnt) ----
// 256 thr = 4 waves, block tile 64t x 256u (uh split x2, merged in softmax).
// A: keys f32 staged by global_load_lds into 3 LDS bufs (16 KB each), issued
//    TWO k-tiles ahead. Granule swizzle phys = g ^ (row&7) applied on the
//    per-lane GLOBAL source address (LDS stays DMA-linear), undone on ds_read.
// B: Wm bf16 (L2-resident) reg double-buffer, loaded one k-tile ahead.
// Waits: end-of-iter s_waitcnt vmcnt(12) = "A(kt+1) landed, this iter's 12
// loads still in flight"; raw s_barrier (no full drain).
#define TM 64
#define BKt 64

__global__ __launch_bounds__(256, 3) void score_kernel(const float* __restrict__ keys,
                                                       const unsigned short* __restrict__ WmB,
                                                       const float* __restrict__ pq,
                                                       const float* __restrict__ Wa,
                                                       float* __restrict__ spart) {
    __shared__ __align__(16) float Alds[3][TM * BKt];   // 48 KB
    __shared__ float sc_lds[4][TM];

    const int tid = threadIdx.x;
    const int lane = tid & 63;
    const int w = tid >> 6;
    const int lc = lane & 31;
    const int l5 = lane >> 5;
    const int b = blockIdx.y;
    const int tt = blockIdx.x >> 1;
    const int uh = blockIdx.x & 1;
    const int t0 = tt * TM;
    const int u0 = uh * 256 + w * 64;

    // ---- staging geometry: wave w covers rows w*16..w*16+16, 4 instrs x 1KB.
    // instr i rows w*16+i*4..+4; lane l -> row +(l>>4), phys granule l&15.
    // source granule = (l&15) ^ (row&7), row&7 = (i&1)*4 + (l>>4).
    const float* srcW = keys + (size_t)(b * Tn + t0 + w * 16) * MSn;
    const int vo0 = (lane >> 4) * MSn + (((lane & 15) ^ (lane >> 4)) << 2);
    const int vo1 = (lane >> 4) * MSn + (((lane & 15) ^ (4 + (lane >> 4))) << 2);

    const unsigned short* gB0 = WmB + ((size_t)(u0 + lc)) * MSn + l5 * 8;
    const unsigned short* gB1 = gB0 + (size_t)32 * MSn;

    f32x16 acc[2][2];
    #pragma unroll
    for (int mf = 0; mf < 2; ++mf)
        #pragma unroll
        for (int nf = 0; nf < 2; ++nf)
            #pragma unroll
            for (int r = 0; r < 16; ++r) acc[mf][nf][r] = 0.f;

    bf16x8 breg[2][4][2];

    // ---- prologue: DMA A0 (4), A1 (4), B0 regs (8); wait A0 (12 newer ok)
    {
        const float* s0 = srcW;
        GLOAD(s0 + 0 * 2048 + vo0, (char*)&Alds[0][0] + w * 4096 + 0 * 1024);
        GLOAD(s0 + 1 * 2048 + vo1, (char*)&Alds[0][0] + w * 4096 + 1 * 1024);
        GLOAD(s0 + 2 * 2048 + vo0, (char*)&Alds[0][0] + w * 4096 + 2 * 1024);
        GLOAD(s0 + 3 * 2048 + vo1, (char*)&Alds[0][0] + w * 4096 + 3 * 1024);
        __builtin_amdgcn_sched_barrier(0);
        const float* s1 = srcW + BKt;
        GLOAD(s1 + 0 * 2048 + vo0, (char*)&Alds[1][0] + w * 4096 + 0 * 1024);
        GLOAD(s1 + 1 * 2048 + vo1, (char*)&Alds[1][0] + w * 4096 + 1 * 1024);
        GLOAD(s1 + 2 * 2048 + vo0, (char*)&Alds[1][0] + w * 4096 + 2 * 1024);
        GLOAD(s1 + 3 * 2048 + vo1, (char*)&Alds[1][0] + w * 4096 + 3 * 1024);
        __builtin_amdgcn_sched_barrier(0);
        #pragma unroll
        for (int ks = 0; ks < 4; ++ks) {
            breg[0][ks][0] = *(const bf16x8*)(gB0 + ks * 16);
            breg[0][ks][1] = *(const bf16x8*)(gB1 + ks * 16);
        }
        __builtin_amdgcn_sched_barrier(0);
    }
    PIPE_BAR(12);

    #pragma unroll
    for (int kt = 0; kt < 8; ++kt) {
        // 1) DMA A(kt+2) -> buf (kt+2)%3 (readers finished at end-of-(kt-1) bar)
        if (kt < 6) {
            const float* g = srcW + (kt + 2) * BKt;
            char* d = (char*)&Alds[(kt + 2) % 3][0] + w * 4096;
            GLOAD(g + 0 * 2048 + vo0, d + 0 * 1024);
            GLOAD(g + 1 * 2048 + vo1, d + 1 * 1024);
            GLOAD(g + 2 * 2048 + vo0, d + 2 * 1024);
            GLOAD(g + 3 * 2048 + vo1, d + 3 * 1024);
            __builtin_amdgcn_sched_barrier(0);
        }
        // 2) B(kt+1) -> reg dbuf (consumed next iter; counted wait then ~free)
        if (kt < 7) {
            #pragma unroll
            for (int ks = 0; ks < 4; ++ks) {
                breg[(kt + 1) & 1][ks][0] = *(const bf16x8*)(gB0 + (kt + 1) * BKt + ks * 16);
                breg[(kt + 1) & 1][ks][1] = *(const bf16x8*)(gB1 + (kt + 1) * BKt + ks * 16);
            }
            __builtin_amdgcn_sched_barrier(0);
        }

        // 3) MFMA on A[kt] (LDS, swizzle-undone ds_read + cvt_pk) x B[kt]
        {
            const float* lA = &Alds[kt % 3][0];
            #pragma unroll
            for (int ks = 0; ks < 4; ++ks) {
                bf16x8 af[2];
                #pragma unroll
                for (int mf = 0; mf < 2; ++mf) {
                    int r = mf * 32 + lc;
                    int g0 = (ks * 4 + l5 * 2) ^ (r & 7);
                    int g1 = g0 ^ 1;
                    float4 f0 = *(const float4*)(lA + r * BKt + g0 * 4);
                    float4 f1 = *(const float4*)(lA + r * BKt + g1 * 4);
                    af[mf] = cvt8(f0, f1);
                }
                #pragma unroll
                for (int mf = 0; mf < 2; ++mf)
                    #pragma unroll
                    for (int nf = 0; nf < 2; ++nf)
                        acc[mf][nf] = __builtin_amdgcn_mfma_f32_32x32x16_bf16(
                            af[mf], breg[kt & 1][ks][nf], acc[mf][nf], 0, 0, 0);
            }
        }

        // 4) counted-vmcnt barrier: A(kt+1) must be landed before next iter's
        //    ds_reads; leave this iter's (up to 12) loads in flight.
        if (kt < 6)      PIPE_BAR(12);
        else if (kt == 6) PIPE_BAR(8);
        // kt == 7: fall through to epilogue (own __syncthreads)
    }

    // ---- epilogue: partial score = sum_u tanh(vals + pq[u]) * Wa[u]
    // C layout: col(u) = lc, row(t) = mf*32 + (r&3) + 8*(r>>2) + 4*l5
    float pqv[2], wav[2];
    #pragma unroll
    for (int nf = 0; nf < 2; ++nf) {
        int u = u0 + nf * 32 + lc;
        pqv[nf] = pq[(size_t)b * Un + u];
        wav[nf] = Wa[u];
    }
    #pragma unroll
    for (int mf = 0; mf < 2; ++mf) {
        #pragma unroll
        for (int r = 0; r < 16; ++r) {
            float s = tanh_fast(acc[mf][0][r] + pqv[0]) * wav[0]
                    + tanh_fast(acc[mf][1][r] + pqv[1]) * wav[1];
            s += __shfl_xor(s, 16);
            s += __shfl_xor(s, 8);
            s += __shfl_xor(s, 4);
            s += __shfl_xor(s, 2);
            s += __shfl_xor(s, 1);
            if (lc == 0)
                sc_lds[w][mf * 32 + (r & 3) + 8 * (r >> 2) + 4 * l5] = s;
        }
    }
    __syncthreads();
    if (tid < TM) {
        float s = sc_lds[0][tid] + sc_lds[1][tid] + sc_lds[2][tid] + sc_lds[3][tid];
        spart[((size_t)(uh * Bn + b)) * Tn + t0 + tid] = s;
    }
}

// ---------------- merge partials + softmax ----------------
__global__ __launch_bounds__(256) void softmax_kernel(const float* __restrict__ spart,
                                                      float* __restrict__ score_out,
                                                      float* __restrict__ weight) {
    const int b = blockIdx.x, tid = threadIdx.x;
    const int lane = tid & 63, wid = tid >> 6;
    __shared__ float red[4];
    const float* s0 = spart + (size_t)b * Tn;
    const float* s1 = spart + ((size_t)(Bn + b)) * Tn;
    float v[8];
    float mx = -1e30f;
    #pragma unroll
    for (int i = 0; i < 8; ++i) {
        int t = tid + i * 256;
        v[i] = s0[t] + s1[t];
        score_out[(size_t)b * Tn + t] = v[i];
        mx = fmaxf(mx, v[i]);
    }
    #pragma unroll
    for (int off = 32; off; off >>= 1) mx = fmaxf(mx, __shfl_xor(mx, off));
    if (lane == 0) red[wid] = mx;
    __syncthreads();
    mx = fmaxf(fmaxf(red[0], red[1]), fmaxf(red[2], red[3]));
    float sum = 0.f;
    #pragma unroll
    for (int i = 0; i < 8; ++i) { v[i] = expf(v[i] - mx); sum += v[i]; }
    #pragma unroll
    for (int off = 32; off; off >>= 1) sum += __shfl_xor(sum, off);
    __syncthreads();
    if (lane == 0) red[wid] = sum;
    __syncthreads();
    sum = red[0] + red[1] + red[2] + red[3];
    float inv = 1.f / sum;
    #pragma unroll
    for (int i = 0; i < 8; ++i) weight[(size_t)b * Tn + tid + i * 256] = v[i] * inv;
}

// ---------------- context partials: 32 t-chunks per batch, float4/lane ----------------
#define NCH 32
__global__ __launch_bounds__(128) void ctx_partial_kernel(const float* __restrict__ keys,
                                                          const float* __restrict__ weight,
                                                          float* __restrict__ partial) {
    __shared__ float wl[64];
    const int b = blockIdx.x, chunk = blockIdx.y, tid = threadIdx.x;
    const int t0 = chunk * 64;
    if (tid < 64) wl[tid] = weight[(size_t)b * Tn + t0 + tid];
    __syncthreads();
    float4 acc = { 0.f, 0.f, 0.f, 0.f };
    const float4* kp = (const float4*)(keys + ((size_t)b * Tn + t0) * MSn) + tid;
    #pragma unroll 4
    for (int t = 0; t < 64; ++t) {
        float4 kv = kp[(size_t)t * (MSn / 4)];
        float w = wl[t];
        acc.x += w * kv.x;
        acc.y += w * kv.y;
        acc.z += w * kv.z;
        acc.w += w * kv.w;
    }
    *(float4*)&partial[((size_t)b * NCH + chunk) * MSn + tid * 4] = acc;
}

// ---------------- reduce partials -> total_context ----------------
__global__ __launch_bounds__(512) void ctx_reduce_kernel(const float* __restrict__ partial,
                                                         float* __restrict__ ctx) {
    const int b = blockIdx.x, m = threadIdx.x;
    float s = 0.f;
    #pragma unroll
    for (int c = 0; c < NCH; ++c) s += partial[((size_t)b * NCH + c) * MSn + m];
    ctx[(size_t)b * MSn + m] = s;
}

extern "C" void kernel_launch(void* const* d_in, const int* in_sizes, int n_in,
                              void* d_out, int out_size, void* d_ws, size_t ws_size,
                              hipStream_t stream) {
    const float* query = (const float*)d_in[0];
    const float* keys  = (const float*)d_in[1];
    const float* Wq    = (const float*)d_in[2];
    const float* Wm    = (const float*)d_in[3];
    const float* Wa    = (const float*)d_in[4];

    float* ctx_out   = (float*)d_out;                    // [64][512]
    float* score_out = (float*)d_out + (size_t)Bn * MSn; // [64][2048]

    char* ws = (char*)d_ws;
    float* ws_pq      = (float*)(ws);                    // 128 KB
    float* ws_weight  = (float*)(ws + 131072);           // 512 KB
    float* ws_spart   = (float*)(ws + 655360);           // 1 MB  [2][64][2048]
    float* ws_partial = (float*)(ws + 1703936);          // 4 MB  [64][32][512]
    unsigned short* ws_wmbf = (unsigned short*)(ws + 5898240);  // 512 KB

    cvt_kernel<<<(Un * MSn / 4) / 256, 256, 0, stream>>>(Wm, ws_wmbf);
    pq_kernel<<<dim3(Bn, 4), 128, 0, stream>>>(query, Wq, ws_pq);
    score_kernel<<<dim3((Tn / TM) * 2, Bn), 256, 0, stream>>>(keys, ws_wmbf, ws_pq, Wa, ws_spart);
    softmax_kernel<<<Bn, 256, 0, stream>>>(ws_spart, score_out, ws_weight);
    ctx_partial_kernel<<<dim3(Bn, NCH), 128, 0, stream>>>(keys, ws_weight, ws_partial);
    ctx_reduce_kernel<<<Bn, 512, 0, stream>>>(ws_partial, ctx_out);
}

// Round 7
// 238.574 us; speedup vs baseline: 1.1906x; 1.1787x over previous
//
#include <hip/hip_runtime.h>
#include <cstdint>
#include <cstddef>

#define Bn 64
#define Tn 2048
#define Un 512
#define QSn 512
#define MSn 512

using f32x16 = __attribute__((ext_vector_type(16))) float;
using bf16x8 = __attribute__((ext_vector_type(8))) short;

__device__ __forceinline__ unsigned short f2bf(float x) {
    unsigned int u = __float_as_uint(x);
    u += 0x7FFFu + ((u >> 16) & 1u);
    return (unsigned short)(u >> 16);
}

__device__ __forceinline__ unsigned int pk2bf(float lo, float hi) {
    unsigned int r;
    asm("v_cvt_pk_bf16_f32 %0, %1, %2" : "=v"(r) : "v"(lo), "v"(hi));
    return r;
}

__device__ __forceinline__ bf16x8 cvt8(float4 a, float4 b) {
    union { unsigned int u[4]; bf16x8 v; } r;
    r.u[0] = pk2bf(a.x, a.y);
    r.u[1] = pk2bf(a.z, a.w);
    r.u[2] = pk2bf(b.x, b.y);
    r.u[3] = pk2bf(b.z, b.w);
    return r.v;
}

__device__ __forceinline__ float tanh_fast(float x) {
    float e = exp2f(x * 2.885390043258667f);   // e^{2x}
    return 1.f - 2.f * __builtin_amdgcn_rcpf(e + 1.f);
}

// async global->LDS, 16B per lane; LDS dest = wave-uniform base + lane*16
#define GLOAD(G, L) __builtin_amdgcn_global_load_lds( \
    (const __attribute__((address_space(1))) void*)(G), \
    (__attribute__((address_space(3))) void*)(L), 16, 0, 0)

// ---------------- Wm f32 -> bf16 pre-convert ----------------
__global__ __launch_bounds__(256) void cvt_kernel(const float* __restrict__ src,
                                                  unsigned short* __restrict__ dst) {
    int i = blockIdx.x * 256 + threadIdx.x;  // one float4 per thread
    float4 v = *(const float4*)(src + (size_t)i * 4);
    ushort4 h = { f2bf(v.x), f2bf(v.y), f2bf(v.z), f2bf(v.w) };
    *(ushort4*)&dst[(size_t)i * 4] = h;
}

// ---------------- pq = query @ Wq^T : [B,U] ----------------
__global__ __launch_bounds__(128) void pq_kernel(const float* __restrict__ query,
                                                 const float* __restrict__ Wq,
                                                 float* __restrict__ pq) {
    __shared__ float ql[QSn];
    const int b = blockIdx.x;
    const int quad = blockIdx.y;
    const int tid = threadIdx.x;
    for (int i = tid; i < QSn; i += 128) ql[i] = query[(size_t)b * QSn + i];
    __syncthreads();
    const int u = quad * 128 + tid;
    const float* w = Wq + (size_t)u * QSn;
    float a0 = 0.f, a1 = 0.f;
    #pragma unroll 4
    for (int k = 0; k < QSn; k += 8) {
        float4 w0 = *(const float4*)(w + k);
        float4 w1 = *(const float4*)(w + k + 4);
        float4 q0 = *(const float4*)(ql + k);
        float4 q1 = *(const float4*)(ql + k + 4);
        a0 += w0.x * q0.x + w0.y * q0.y + w0.z * q0.z + w0.w * q0.w;
        a1 += w1.x * q1.x + w1.y * q1.y + w1.z * q1.z + w1.w * q1.w;
    }
    pq[(size_t)b * Un + u] = a0 + a1;
}

// ---------------- fused score GEMM (v7: all-LDS operands, m97 2-barrier) ----
// 256 thr = 4 waves (2m x 2n). Block tile 128t x 128u (uh split x4, merged in
// softmax). Per k-step (BK=64):
//   A (keys f32) -> LDS 32 KB via 8 GLOAD/wave, source-XOR-swizzled granules
//   B (Wm bf16)  -> LDS 16 KB via 4 GLOAD/wave, coalesced (NO per-lane gather!)
//   barrier; 16 A-ds_read+cvt, 8 B-ds_read, 16 MFMA per wave; barrier.
// 48 KB LDS single-buffered -> 3 blocks/CU; overlap comes from co-resident
// blocks (m97 pattern: 874 TF with exactly this loop shape).
__global__ __launch_bounds__(256, 3) void score_kernel(const float* __restrict__ keys,
                                                       const unsigned short* __restrict__ WmB,
                                                       const float* __restrict__ pq,
                                                       const float* __restrict__ Wa,
                                                       float* __restrict__ spart) {
    __shared__ __align__(16) float Af[128 * 64];           // 32 KB
    __shared__ __align__(16) unsigned short Bh[128 * 64];  // 16 KB
    __shared__ float sc_lds[2][128];

    const int tid = threadIdx.x;
    const int lane = tid & 63;
    const int w = tid >> 6;
    const int wm = w >> 1;          // 0..1
    const int wn = w & 1;           // 0..1
    const int lc = lane & 31;
    const int l5 = lane >> 5;
    const int b = blockIdx.y;
    const int tt = blockIdx.x >> 2;
    const int uh = blockIdx.x & 3;
    const int t0 = tt * 128;
    const int u0 = uh * 128;

    // ---- A staging: wave w stages rows w*32..+32 as 8 GLOADs of 4 rows (1KB).
    // lane -> row += (lane>>4), phys granule lane&15 (16B of 4 f32).
    // source granule = phys ^ (row&7); row&7 = (i&1)*4 + (lane>>4).
    const int arow = lane >> 4;
    const int aco0 = (((lane & 15) ^ arow) << 2);         // i even, elems
    const int aco1 = (((lane & 15) ^ (4 + arow)) << 2);   // i odd
    const float* gA = keys + ((size_t)(b * Tn) + t0 + w * 32 + arow) * MSn;

    // ---- B staging: wave w stages rows w*32..+32 as 4 GLOADs of 8 rows (1KB).
    // lane -> row += (lane>>3), phys granule lane&7 (16B of 8 bf16).
    // source granule = phys ^ (row&7); row&7 = lane>>3.
    const int brow = lane >> 3;
    const int bco = (((lane & 7) ^ brow) << 3);           // elems
    const unsigned short* gB = WmB + ((size_t)(u0 + w * 32 + brow)) * MSn + bco;

    char* aDst = (char*)Af + w * 8192;
    char* bDst = (char*)Bh + w * 4096;

    f32x16 acc[2][2];
    #pragma unroll
    for (int mf = 0; mf < 2; ++mf)
        #pragma unroll
        for (int nf = 0; nf < 2; ++nf)
            #pragma unroll
            for (int r = 0; r < 16; ++r) acc[mf][nf][r] = 0.f;

    #define STAGE(KT) do { \
        const float* ga_ = gA + (KT) * 64; \
        _Pragma("unroll") \
        for (int i = 0; i < 8; ++i) \
            GLOAD(ga_ + (size_t)i * 4 * MSn + ((i & 1) ? aco1 : aco0), aDst + i * 1024); \
        const unsigned short* gb_ = gB + (KT) * 64; \
        _Pragma("unroll") \
        for (int i = 0; i < 4; ++i) \
            GLOAD(gb_ + (size_t)i * 8 * MSn, bDst + i * 1024); \
    } while (0)

    STAGE(0);

    #pragma unroll
    for (int kt = 0; kt < 8; ++kt) {
        __syncthreads();   // staging of kt landed (vmcnt drain at barrier)

        #pragma unroll
        for (int ks = 0; ks < 4; ++ks) {
            bf16x8 af[2], bfr[2];
            #pragma unroll
            for (int mf = 0; mf < 2; ++mf) {
                int r = wm * 64 + mf * 32 + lc;
                int g0 = (ks * 4 + l5 * 2) ^ (r & 7);
                int g1 = (ks * 4 + l5 * 2 + 1) ^ (r & 7);
                float4 f0 = *(const float4*)&Af[r * 64 + g0 * 4];
                float4 f1 = *(const float4*)&Af[r * 64 + g1 * 4];
                af[mf] = cvt8(f0, f1);
            }
            #pragma unroll
            for (int nf = 0; nf < 2; ++nf) {
                int ru = wn * 64 + nf * 32 + lc;
                int bg = (ks * 2 + l5) ^ (ru & 7);
                bfr[nf] = *(const bf16x8*)&Bh[ru * 64 + bg * 8];
            }
            #pragma unroll
            for (int mf = 0; mf < 2; ++mf)
                #pragma unroll
                for (int nf = 0; nf < 2; ++nf)
                    acc[mf][nf] = __builtin_amdgcn_mfma_f32_32x32x16_bf16(
                        af[mf], bfr[nf], acc[mf][nf], 0, 0, 0);
        }

        __syncthreads();   // all reads done before overwrite
        if (kt < 7) STAGE(kt + 1);
    }
    #undef STAGE

    // ---- epilogue: partial score = sum_u tanh(vals + pq[u]) * Wa[u]
    // C layout: col(u) = lc, row(t) = mf*32 + (r&3) + 8*(r>>2) + 4*l5
    float pqv[2], wav[2];
    #pragma unroll
    for (int nf = 0; nf < 2; ++nf) {
        int u = u0 + wn * 64 + nf * 32 + lc;
        pqv[nf] = pq[(size_t)b * Un + u];
        wav[nf] = Wa[u];
    }
    #pragma unroll
    for (int mf = 0; mf < 2; ++mf) {
        #pragma unroll
        for (int r = 0; r < 16; ++r) {
            float s = tanh_fast(acc[mf][0][r] + pqv[0]) * wav[0]
                    + tanh_fast(acc[mf][1][r] + pqv[1]) * wav[1];
            s += __shfl_xor(s, 16);
            s += __shfl_xor(s, 8);
            s += __shfl_xor(s, 4);
            s += __shfl_xor(s, 2);
            s += __shfl_xor(s, 1);
            if (lc == 0)
                sc_lds[wn][wm * 64 + mf * 32 + (r & 3) + 8 * (r >> 2) + 4 * l5] = s;
        }
    }
    __syncthreads();
    if (tid < 128) {
        spart[((size_t)(uh * Bn + b)) * Tn + t0 + tid] = sc_lds[0][tid] + sc_lds[1][tid];
    }
}

// ---------------- merge 4 partials + softmax ----------------
__global__ __launch_bounds__(256) void softmax_kernel(const float* __restrict__ spart,
                                                      float* __restrict__ score_out,
                                                      float* __restrict__ weight) {
    const int b = blockIdx.x, tid = threadIdx.x;
    const int lane = tid & 63, wid = tid >> 6;
    __shared__ float red[4];
    const float* s0 = spart + (size_t)b * Tn;
    const float* s1 = spart + ((size_t)(Bn + b)) * Tn;
    const float* s2 = spart + ((size_t)(2 * Bn + b)) * Tn;
    const float* s3 = spart + ((size_t)(3 * Bn + b)) * Tn;
    float v[8];
    float mx = -1e30f;
    #pragma unroll
    for (int i = 0; i < 8; ++i) {
        int t = tid + i * 256;
        v[i] = (s0[t] + s1[t]) + (s2[t] + s3[t]);
        score_out[(size_t)b * Tn + t] = v[i];
        mx = fmaxf(mx, v[i]);
    }
    #pragma unroll
    for (int off = 32; off; off >>= 1) mx = fmaxf(mx, __shfl_xor(mx, off));
    if (lane == 0) red[wid] = mx;
    __syncthreads();
    mx = fmaxf(fmaxf(red[0], red[1]), fmaxf(red[2], red[3]));
    float sum = 0.f;
    #pragma unroll
    for (int i = 0; i < 8; ++i) { v[i] = expf(v[i] - mx); sum += v[i]; }
    #pragma unroll
    for (int off = 32; off; off >>= 1) sum += __shfl_xor(sum, off);
    __syncthreads();
    if (lane == 0) red[wid] = sum;
    __syncthreads();
    sum = red[0] + red[1] + red[2] + red[3];
    float inv = 1.f / sum;
    #pragma unroll
    for (int i = 0; i < 8; ++i) weight[(size_t)b * Tn + tid + i * 256] = v[i] * inv;
}

// ---------------- context partials: 32 t-chunks per batch, float4/lane ----------------
#define NCH 32
__global__ __launch_bounds__(128) void ctx_partial_kernel(const float* __restrict__ keys,
                                                          const float* __restrict__ weight,
                                                          float* __restrict__ partial) {
    __shared__ float wl[64];
    const int b = blockIdx.x, chunk = blockIdx.y, tid = threadIdx.x;
    const int t0 = chunk * 64;
    if (tid < 64) wl[tid] = weight[(size_t)b * Tn + t0 + tid];
    __syncthreads();
    float4 acc = { 0.f, 0.f, 0.f, 0.f };
    const float4* kp = (const float4*)(keys + ((size_t)b * Tn + t0) * MSn) + tid;
    #pragma unroll 4
    for (int t = 0; t < 64; ++t) {
        float4 kv = kp[(size_t)t * (MSn / 4)];
        float w = wl[t];
        acc.x += w * kv.x;
        acc.y += w * kv.y;
        acc.z += w * kv.z;
        acc.w += w * kv.w;
    }
    *(float4*)&partial[((size_t)b * NCH + chunk) * MSn + tid * 4] = acc;
}

// ---------------- reduce partials -> total_context ----------------
__global__ __launch_bounds__(512) void ctx_reduce_kernel(const float* __restrict__ partial,
                                                         float* __restrict__ ctx) {
    const int b = blockIdx.x, m = threadIdx.x;
    float s = 0.f;
    #pragma unroll
    for (int c = 0; c < NCH; ++c) s += partial[((size_t)b * NCH + c) * MSn + m];
    ctx[(size_t)b * MSn + m] = s;
}

extern "C" void kernel_launch(void* const* d_in, const int* in_sizes, int n_in,
                              void* d_out, int out_size, void* d_ws, size_t ws_size,
                              hipStream_t stream) {
    const float* query = (const float*)d_in[0];
    const float* keys  = (const float*)d_in[1];
    const float* Wq    = (const float*)d_in[2];
    const float* Wm    = (const float*)d_in[3];
    const float* Wa    = (const float*)d_in[4];

    float* ctx_out   = (float*)d_out;                    // [64][512]
    float* score_out = (float*)d_out + (size_t)Bn * MSn; // [64][2048]

    char* ws = (char*)d_ws;
    float* ws_pq      = (float*)(ws);                    // 128 KB
    float* ws_weight  = (float*)(ws + 131072);           // 512 KB
    float* ws_spart   = (float*)(ws + 655360);           // 2 MB  [4][64][2048]
    float* ws_partial = (float*)(ws + 2752512);          // 4 MB  [64][32][512]
    unsigned short* ws_wmbf = (unsigned short*)(ws + 6946816);  // 512 KB

    cvt_kernel<<<(Un * MSn / 4) / 256, 256, 0, stream>>>(Wm, ws_wmbf);
    pq_kernel<<<dim3(Bn, 4), 128, 0, stream>>>(query, Wq, ws_pq);
    score_kernel<<<dim3(64, Bn), 256, 0, stream>>>(keys, ws_wmbf, ws_pq, Wa, ws_spart);
    softmax_kernel<<<Bn, 256, 0, stream>>>(ws_spart, score_out, ws_weight);
    ctx_partial_kernel<<<dim3(Bn, NCH), 128, 0, stream>>>(keys, ws_weight, ws_partial);
    ctx_reduce_kernel<<<Bn, 512, 0, stream>>>(ws_partial, ctx_out);
}

// Round 8
// 219.582 us; speedup vs baseline: 1.2936x; 1.0865x over previous
//
#include <hip/hip_runtime.h>
#include <cstdint>
#include <cstddef>

#define Bn 64
#define Tn 2048
#define Un 512
#define QSn 512
#define MSn 512

using f32x16 = __attribute__((ext_vector_type(16))) float;
using bf16x8 = __attribute__((ext_vector_type(8))) short;

__device__ __forceinline__ unsigned short f2bf(float x) {
    unsigned int u = __float_as_uint(x);
    u += 0x7FFFu + ((u >> 16) & 1u);
    return (unsigned short)(u >> 16);
}

__device__ __forceinline__ float b2f(unsigned short h) {
    return __uint_as_float(((unsigned int)h) << 16);
}

__device__ __forceinline__ unsigned int pk2bf(float lo, float hi) {
    unsigned int r;
    asm("v_cvt_pk_bf16_f32 %0, %1, %2" : "=v"(r) : "v"(lo), "v"(hi));
    return r;
}

__device__ __forceinline__ bf16x8 cvt8(float4 a, float4 b) {
    union { unsigned int u[4]; bf16x8 v; } r;
    r.u[0] = pk2bf(a.x, a.y);
    r.u[1] = pk2bf(a.z, a.w);
    r.u[2] = pk2bf(b.x, b.y);
    r.u[3] = pk2bf(b.z, b.w);
    return r.v;
}

__device__ __forceinline__ float tanh_fast(float x) {
    float e = exp2f(x * 2.885390043258667f);   // e^{2x}
    return 1.f - 2.f * __builtin_amdgcn_rcpf(e + 1.f);
}

// async global->LDS, 16B per lane; LDS dest = wave-uniform base + lane*16
#define GLOAD(G, L) __builtin_amdgcn_global_load_lds( \
    (const __attribute__((address_space(1))) void*)(G), \
    (__attribute__((address_space(3))) void*)(L), 16, 0, 0)

// ---------------- Wm f32 -> bf16 pre-convert ----------------
__global__ __launch_bounds__(256) void cvt_kernel(const float* __restrict__ src,
                                                  unsigned short* __restrict__ dst) {
    int i = blockIdx.x * 256 + threadIdx.x;  // one float4 per thread
    float4 v = *(const float4*)(src + (size_t)i * 4);
    ushort4 h = { f2bf(v.x), f2bf(v.y), f2bf(v.z), f2bf(v.w) };
    *(ushort4*)&dst[(size_t)i * 4] = h;
}

// ---------------- keys f32 -> bf16 pre-convert (256 MB -> 128 MB) ----------------
__global__ __launch_bounds__(256) void cvtkeys_kernel(const float* __restrict__ src,
                                                      unsigned short* __restrict__ dst) {
    size_t i = ((size_t)blockIdx.x * 256 + threadIdx.x) * 8;  // 8 f32 per thread
    float4 v0 = *(const float4*)(src + i);
    float4 v1 = *(const float4*)(src + i + 4);
    union { unsigned int u[4]; bf16x8 v; } h;
    h.u[0] = pk2bf(v0.x, v0.y);
    h.u[1] = pk2bf(v0.z, v0.w);
    h.u[2] = pk2bf(v1.x, v1.y);
    h.u[3] = pk2bf(v1.z, v1.w);
    *(bf16x8*)&dst[i] = h.v;
}

// ---------------- pq = query @ Wq^T : [B,U] ----------------
__global__ __launch_bounds__(128) void pq_kernel(const float* __restrict__ query,
                                                 const float* __restrict__ Wq,
                                                 float* __restrict__ pq) {
    __shared__ float ql[QSn];
    const int b = blockIdx.x;
    const int quad = blockIdx.y;
    const int tid = threadIdx.x;
    for (int i = tid; i < QSn; i += 128) ql[i] = query[(size_t)b * QSn + i];
    __syncthreads();
    const int u = quad * 128 + tid;
    const float* w = Wq + (size_t)u * QSn;
    float a0 = 0.f, a1 = 0.f;
    #pragma unroll 4
    for (int k = 0; k < QSn; k += 8) {
        float4 w0 = *(const float4*)(w + k);
        float4 w1 = *(const float4*)(w + k + 4);
        float4 q0 = *(const float4*)(ql + k);
        float4 q1 = *(const float4*)(ql + k + 4);
        a0 += w0.x * q0.x + w0.y * q0.y + w0.z * q0.z + w0.w * q0.w;
        a1 += w1.x * q1.x + w1.y * q1.y + w1.z * q1.z + w1.w * q1.w;
    }
    pq[(size_t)b * Un + u] = a0 + a1;
}

// ---------------- fused score GEMM (v8: bf16 A AND B via GLOAD, m97 shape) ----
// 256 thr = 4 waves (2m x 2n). Block tile 128t x 128u (uh split x4, merged in
// softmax). Per k-step (BK=64): A (keys bf16) + B (Wm bf16) each 16 KB via 4
// GLOAD/wave, source-XOR-swizzled granules; barrier; per wave: 16 ds_read_b128
// + 16 MFMA (NO cvt in loop); barrier. 33 KB LDS -> 3 blocks/CU.
__global__ __launch_bounds__(256, 3) void score_kernel_bf16(const unsigned short* __restrict__ keysB,
                                                            const unsigned short* __restrict__ WmB,
                                                            const float* __restrict__ pq,
                                                            const float* __restrict__ Wa,
                                                            float* __restrict__ spart) {
    __shared__ __align__(16) unsigned short Ah[128 * 64];  // 16 KB
    __shared__ __align__(16) unsigned short Bh[128 * 64];  // 16 KB
    __shared__ float sc_lds[2][128];

    const int tid = threadIdx.x;
    const int lane = tid & 63;
    const int w = tid >> 6;
    const int wm = w >> 1;
    const int wn = w & 1;
    const int lc = lane & 31;
    const int l5 = lane >> 5;
    const int b = blockIdx.y;
    const int tt = blockIdx.x >> 2;
    const int uh = blockIdx.x & 3;
    const int t0 = tt * 128;
    const int u0 = uh * 128;

    // staging geometry (shared by A and B): wave w stages rows w*32..+32 as
    // 4 GLOADs of 8 rows (1 KB each). lane -> row += lane>>3, phys granule
    // lane&7 (16B = 8 bf16). source granule = phys ^ (row&7), row&7 = lane>>3.
    const int srow = lane >> 3;
    const int sco  = (((lane & 7) ^ srow) << 3);
    const unsigned short* gA = keysB + ((size_t)(b * Tn) + t0 + w * 32 + srow) * MSn + sco;
    const unsigned short* gB = WmB + ((size_t)(u0 + w * 32 + srow)) * MSn + sco;
    char* aDst = (char*)Ah + w * 4096;
    char* bDst = (char*)Bh + w * 4096;

    f32x16 acc[2][2];
    #pragma unroll
    for (int mf = 0; mf < 2; ++mf)
        #pragma unroll
        for (int nf = 0; nf < 2; ++nf)
            #pragma unroll
            for (int r = 0; r < 16; ++r) acc[mf][nf][r] = 0.f;

    #define STAGE8(KT) do { \
        _Pragma("unroll") \
        for (int i = 0; i < 4; ++i) \
            GLOAD(gA + (KT) * 64 + (size_t)i * 8 * MSn, aDst + i * 1024); \
        _Pragma("unroll") \
        for (int i = 0; i < 4; ++i) \
            GLOAD(gB + (KT) * 64 + (size_t)i * 8 * MSn, bDst + i * 1024); \
    } while (0)

    STAGE8(0);

    #pragma unroll
    for (int kt = 0; kt < 8; ++kt) {
        __syncthreads();   // staging of kt landed (vmcnt drain at barrier)

        #pragma unroll
        for (int ks = 0; ks < 4; ++ks) {
            bf16x8 af[2], bfr[2];
            #pragma unroll
            for (int mf = 0; mf < 2; ++mf) {
                int r = wm * 64 + mf * 32 + lc;
                int g = (ks * 2 + l5) ^ (r & 7);
                af[mf] = *(const bf16x8*)&Ah[r * 64 + g * 8];
            }
            #pragma unroll
            for (int nf = 0; nf < 2; ++nf) {
                int ru = wn * 64 + nf * 32 + lc;
                int bg = (ks * 2 + l5) ^ (ru & 7);
                bfr[nf] = *(const bf16x8*)&Bh[ru * 64 + bg * 8];
            }
            #pragma unroll
            for (int mf = 0; mf < 2; ++mf)
                #pragma unroll
                for (int nf = 0; nf < 2; ++nf)
                    acc[mf][nf] = __builtin_amdgcn_mfma_f32_32x32x16_bf16(
                        af[mf], bfr[nf], acc[mf][nf], 0, 0, 0);
        }

        __syncthreads();   // all reads done before overwrite
        if (kt < 7) STAGE8(kt + 1);
    }
    #undef STAGE8

    // epilogue: partial score = sum_u tanh(vals + pq[u]) * Wa[u]
    // C layout: col(u) = lc, row(t) = mf*32 + (r&3) + 8*(r>>2) + 4*l5
    float pqv[2], wav[2];
    #pragma unroll
    for (int nf = 0; nf < 2; ++nf) {
        int u = u0 + wn * 64 + nf * 32 + lc;
        pqv[nf] = pq[(size_t)b * Un + u];
        wav[nf] = Wa[u];
    }
    #pragma unroll
    for (int mf = 0; mf < 2; ++mf) {
        #pragma unroll
        for (int r = 0; r < 16; ++r) {
            float s = tanh_fast(acc[mf][0][r] + pqv[0]) * wav[0]
                    + tanh_fast(acc[mf][1][r] + pqv[1]) * wav[1];
            s += __shfl_xor(s, 16);
            s += __shfl_xor(s, 8);
            s += __shfl_xor(s, 4);
            s += __shfl_xor(s, 2);
            s += __shfl_xor(s, 1);
            if (lc == 0)
                sc_lds[wn][wm * 64 + mf * 32 + (r & 3) + 8 * (r >> 2) + 4 * l5] = s;
        }
    }
    __syncthreads();
    if (tid < 128) {
        spart[((size_t)(uh * Bn + b)) * Tn + t0 + tid] = sc_lds[0][tid] + sc_lds[1][tid];
    }
}

// ---------------- fallback (R7): f32-A score kernel ----------------
__global__ __launch_bounds__(256, 3) void score_kernel_f32(const float* __restrict__ keys,
                                                           const unsigned short* __restrict__ WmB,
                                                           const float* __restrict__ pq,
                                                           const float* __restrict__ Wa,
                                                           float* __restrict__ spart) {
    __shared__ __align__(16) float Af[128 * 64];
    __shared__ __align__(16) unsigned short Bh[128 * 64];
    __shared__ float sc_lds[2][128];

    const int tid = threadIdx.x;
    const int lane = tid & 63;
    const int w = tid >> 6;
    const int wm = w >> 1;
    const int wn = w & 1;
    const int lc = lane & 31;
    const int l5 = lane >> 5;
    const int b = blockIdx.y;
    const int tt = blockIdx.x >> 2;
    const int uh = blockIdx.x & 3;
    const int t0 = tt * 128;
    const int u0 = uh * 128;

    const int arow = lane >> 4;
    const int aco0 = (((lane & 15) ^ arow) << 2);
    const int aco1 = (((lane & 15) ^ (4 + arow)) << 2);
    const float* gA = keys + ((size_t)(b * Tn) + t0 + w * 32 + arow) * MSn;

    const int brow = lane >> 3;
    const int bco = (((lane & 7) ^ brow) << 3);
    const unsigned short* gB = WmB + ((size_t)(u0 + w * 32 + brow)) * MSn + bco;

    char* aDst = (char*)Af + w * 8192;
    char* bDst = (char*)Bh + w * 4096;

    f32x16 acc[2][2];
    #pragma unroll
    for (int mf = 0; mf < 2; ++mf)
        #pragma unroll
        for (int nf = 0; nf < 2; ++nf)
            #pragma unroll
            for (int r = 0; r < 16; ++r) acc[mf][nf][r] = 0.f;

    #define STAGEF(KT) do { \
        const float* ga_ = gA + (KT) * 64; \
        _Pragma("unroll") \
        for (int i = 0; i < 8; ++i) \
            GLOAD(ga_ + (size_t)i * 4 * MSn + ((i & 1) ? aco1 : aco0), aDst + i * 1024); \
        const unsigned short* gb_ = gB + (KT) * 64; \
        _Pragma("unroll") \
        for (int i = 0; i < 4; ++i) \
            GLOAD(gb_ + (size_t)i * 8 * MSn, bDst + i * 1024); \
    } while (0)

    STAGEF(0);

    #pragma unroll
    for (int kt = 0; kt < 8; ++kt) {
        __syncthreads();
        #pragma unroll
        for (int ks = 0; ks < 4; ++ks) {
            bf16x8 af[2], bfr[2];
            #pragma unroll
            for (int mf = 0; mf < 2; ++mf) {
                int r = wm * 64 + mf * 32 + lc;
                int g0 = (ks * 4 + l5 * 2) ^ (r & 7);
                int g1 = (ks * 4 + l5 * 2 + 1) ^ (r & 7);
                float4 f0 = *(const float4*)&Af[r * 64 + g0 * 4];
                float4 f1 = *(const float4*)&Af[r * 64 + g1 * 4];
                af[mf] = cvt8(f0, f1);
            }
            #pragma unroll
            for (int nf = 0; nf < 2; ++nf) {
                int ru = wn * 64 + nf * 32 + lc;
                int bg = (ks * 2 + l5) ^ (ru & 7);
                bfr[nf] = *(const bf16x8*)&Bh[ru * 64 + bg * 8];
            }
            #pragma unroll
            for (int mf = 0; mf < 2; ++mf)
                #pragma unroll
                for (int nf = 0; nf < 2; ++nf)
                    acc[mf][nf] = __builtin_amdgcn_mfma_f32_32x32x16_bf16(
                        af[mf], bfr[nf], acc[mf][nf], 0, 0, 0);
        }
        __syncthreads();
        if (kt < 7) STAGEF(kt + 1);
    }
    #undef STAGEF

    float pqv[2], wav[2];
    #pragma unroll
    for (int nf = 0; nf < 2; ++nf) {
        int u = u0 + wn * 64 + nf * 32 + lc;
        pqv[nf] = pq[(size_t)b * Un + u];
        wav[nf] = Wa[u];
    }
    #pragma unroll
    for (int mf = 0; mf < 2; ++mf) {
        #pragma unroll
        for (int r = 0; r < 16; ++r) {
            float s = tanh_fast(acc[mf][0][r] + pqv[0]) * wav[0]
                    + tanh_fast(acc[mf][1][r] + pqv[1]) * wav[1];
            s += __shfl_xor(s, 16);
            s += __shfl_xor(s, 8);
            s += __shfl_xor(s, 4);
            s += __shfl_xor(s, 2);
            s += __shfl_xor(s, 1);
            if (lc == 0)
                sc_lds[wn][wm * 64 + mf * 32 + (r & 3) + 8 * (r >> 2) + 4 * l5] = s;
        }
    }
    __syncthreads();
    if (tid < 128) {
        spart[((size_t)(uh * Bn + b)) * Tn + t0 + tid] = sc_lds[0][tid] + sc_lds[1][tid];
    }
}

// ---------------- merge 4 partials + softmax ----------------
__global__ __launch_bounds__(256) void softmax_kernel(const float* __restrict__ spart,
                                                      float* __restrict__ score_out,
                                                      float* __restrict__ weight) {
    const int b = blockIdx.x, tid = threadIdx.x;
    const int lane = tid & 63, wid = tid >> 6;
    __shared__ float red[4];
    const float* s0 = spart + (size_t)b * Tn;
    const float* s1 = spart + ((size_t)(Bn + b)) * Tn;
    const float* s2 = spart + ((size_t)(2 * Bn + b)) * Tn;
    const float* s3 = spart + ((size_t)(3 * Bn + b)) * Tn;
    float v[8];
    float mx = -1e30f;
    #pragma unroll
    for (int i = 0; i < 8; ++i) {
        int t = tid + i * 256;
        v[i] = (s0[t] + s1[t]) + (s2[t] + s3[t]);
        score_out[(size_t)b * Tn + t] = v[i];
        mx = fmaxf(mx, v[i]);
    }
    #pragma unroll
    for (int off = 32; off; off >>= 1) mx = fmaxf(mx, __shfl_xor(mx, off));
    if (lane == 0) red[wid] = mx;
    __syncthreads();
    mx = fmaxf(fmaxf(red[0], red[1]), fmaxf(red[2], red[3]));
    float sum = 0.f;
    #pragma unroll
    for (int i = 0; i < 8; ++i) { v[i] = expf(v[i] - mx); sum += v[i]; }
    #pragma unroll
    for (int off = 32; off; off >>= 1) sum += __shfl_xor(sum, off);
    __syncthreads();
    if (lane == 0) red[wid] = sum;
    __syncthreads();
    sum = red[0] + red[1] + red[2] + red[3];
    float inv = 1.f / sum;
    #pragma unroll
    for (int i = 0; i < 8; ++i) weight[(size_t)b * Tn + tid + i * 256] = v[i] * inv;
}

// ---------------- context partials ----------------
#define NCH 32
__global__ __launch_bounds__(128) void ctx_partial_bf16(const unsigned short* __restrict__ keysB,
                                                        const float* __restrict__ weight,
                                                        float* __restrict__ partial) {
    __shared__ float wl[64];
    const int b = blockIdx.x, chunk = blockIdx.y, tid = threadIdx.x;
    const int t0 = chunk * 64;
    if (tid < 64) wl[tid] = weight[(size_t)b * Tn + t0 + tid];
    __syncthreads();
    float4 acc = { 0.f, 0.f, 0.f, 0.f };
    const unsigned short* kp = keysB + ((size_t)b * Tn + t0) * MSn + tid * 4;
    #pragma unroll 4
    for (int t = 0; t < 64; ++t) {
        ushort4 kv = *(const ushort4*)&kp[(size_t)t * MSn];
        float w = wl[t];
        acc.x += w * b2f(kv.x);
        acc.y += w * b2f(kv.y);
        acc.z += w * b2f(kv.z);
        acc.w += w * b2f(kv.w);
    }
    *(float4*)&partial[((size_t)b * NCH + chunk) * MSn + tid * 4] = acc;
}

__global__ __launch_bounds__(128) void ctx_partial_f32(const float* __restrict__ keys,
                                                       const float* __restrict__ weight,
                                                       float* __restrict__ partial) {
    __shared__ float wl[64];
    const int b = blockIdx.x, chunk = blockIdx.y, tid = threadIdx.x;
    const int t0 = chunk * 64;
    if (tid < 64) wl[tid] = weight[(size_t)b * Tn + t0 + tid];
    __syncthreads();
    float4 acc = { 0.f, 0.f, 0.f, 0.f };
    const float4* kp = (const float4*)(keys + ((size_t)b * Tn + t0) * MSn) + tid;
    #pragma unroll 4
    for (int t = 0; t < 64; ++t) {
        float4 kv = kp[(size_t)t * (MSn / 4)];
        float w = wl[t];
        acc.x += w * kv.x;
        acc.y += w * kv.y;
        acc.z += w * kv.z;
        acc.w += w * kv.w;
    }
    *(float4*)&partial[((size_t)b * NCH + chunk) * MSn + tid * 4] = acc;
}

// ---------------- reduce partials -> total_context ----------------
__global__ __launch_bounds__(512) void ctx_reduce_kernel(const float* __restrict__ partial,
                                                         float* __restrict__ ctx) {
    const int b = blockIdx.x, m = threadIdx.x;
    float s = 0.f;
    #pragma unroll
    for (int c = 0; c < NCH; ++c) s += partial[((size_t)b * NCH + c) * MSn + m];
    ctx[(size_t)b * MSn + m] = s;
}

extern "C" void kernel_launch(void* const* d_in, const int* in_sizes, int n_in,
                              void* d_out, int out_size, void* d_ws, size_t ws_size,
                              hipStream_t stream) {
    const float* query = (const float*)d_in[0];
    const float* keys  = (const float*)d_in[1];
    const float* Wq    = (const float*)d_in[2];
    const float* Wm    = (const float*)d_in[3];
    const float* Wa    = (const float*)d_in[4];

    float* ctx_out   = (float*)d_out;                    // [64][512]
    float* score_out = (float*)d_out + (size_t)Bn * MSn; // [64][2048]

    char* ws = (char*)d_ws;
    float* ws_pq      = (float*)(ws);                    // 128 KB
    float* ws_weight  = (float*)(ws + 131072);           // 512 KB
    float* ws_spart   = (float*)(ws + 655360);           // 2 MB  [4][64][2048]
    float* ws_partial = (float*)(ws + 2752512);          // 4 MB  [64][32][512]
    unsigned short* ws_wmbf = (unsigned short*)(ws + 6946816);   // 512 KB
    unsigned short* ws_keysB = (unsigned short*)(ws + 7471104);  // 128 MB

    const size_t need = 7471104ull + (size_t)Bn * Tn * MSn * 2ull;

    cvt_kernel<<<(Un * MSn / 4) / 256, 256, 0, stream>>>(Wm, ws_wmbf);
    pq_kernel<<<dim3(Bn, 4), 128, 0, stream>>>(query, Wq, ws_pq);

    if (ws_size >= need) {
        cvtkeys_kernel<<<(Bn * Tn * MSn / 8) / 256, 256, 0, stream>>>(keys, ws_keysB);
        score_kernel_bf16<<<dim3(64, Bn), 256, 0, stream>>>(ws_keysB, ws_wmbf, ws_pq, Wa, ws_spart);
        softmax_kernel<<<Bn, 256, 0, stream>>>(ws_spart, score_out, ws_weight);
        ctx_partial_bf16<<<dim3(Bn, NCH), 128, 0, stream>>>(ws_keysB, ws_weight, ws_partial);
    } else {
        score_kernel_f32<<<dim3(64, Bn), 256, 0, stream>>>(keys, ws_wmbf, ws_pq, Wa, ws_spart);
        softmax_kernel<<<Bn, 256, 0, stream>>>(ws_spart, score_out, ws_weight);
        ctx_partial_f32<<<dim3(Bn, NCH), 128, 0, stream>>>(keys, ws_weight, ws_partial);
    }
    ctx_reduce_kernel<<<Bn, 512, 0, stream>>>(ws_partial, ctx_out);
}